// Round 11
// baseline (3069.790 us; speedup 1.0000x reference)
//
#include <hip/hip_runtime.h>
#include <hip/hip_bf16.h>
#include <math.h>

#define B_ 512
#define S_ 256
#define D_ 256
#define NLOC 50000
#define KX 448      // D + TEMP
#define G4 1024
#define NEGV -1000000000.0f

typedef __attribute__((ext_vector_type(8))) short short8;
typedef __attribute__((ext_vector_type(4))) float f32x4;

__device__ __forceinline__ float sigmoidf_(float x){ return 1.0f/(1.0f+expf(-x)); }
__device__ __forceinline__ float geluf_(float x){ return 0.5f*x*(1.0f+erff(x*0.70710678118654752f)); }
__device__ __forceinline__ unsigned short f2bf_(float x){
  __hip_bfloat16 h = __float2bfloat16(x);
  return *(unsigned short*)&h;
}
__device__ __forceinline__ float bf2f_(unsigned short u){
  __hip_bfloat16 h = *(__hip_bfloat16*)&u;
  return __bfloat162float(h);
}
// fast sigmoid: ~2e-7 rel
__device__ __forceinline__ float fsig_(float x){
  return __fdividef(1.0f, 1.0f + __expf(-x));
}
// cancellation-free fast tanh
__device__ __forceinline__ float ftanh2_(float x){
  float ax = fabsf(x);
  float x2 = x*x;
  float tp = x*(1.0f + x2*(-0.3333333333f + x2*(0.1333333333f + x2*(-0.05396825397f))));
  float e  = __expf(2.0f*fminf(ax, 15.0f));
  float te = 1.0f - __fdividef(2.0f, e + 1.0f);
  te = copysignf(te, x);
  return ax < 0.25f ? tp : te;
}
__device__ __forceinline__ void gld_lds16_(const void* gsrc, void* ldst){
  __builtin_amdgcn_global_load_lds((const __attribute__((address_space(1))) void*)gsrc,
                                   (__attribute__((address_space(3))) void*)ldst, 16, 0, 0);
}

// ---- init flag ----
__global__ void k_init(int* flag){
  if (blockIdx.x==0 && threadIdx.x==0) *flag = 0;
}

// ---- detect mask layout ----
__global__ void k_detect(const unsigned char* m, int* flag){
  int i = blockIdx.x*256 + threadIdx.x;
  if ((i & 1) && i < B_*S_ && m[i]) atomicOr(flag, 1);
}

// ---- seq_lens[b] = count(mask row) - 1 ----
__global__ void k_seqlen(const void* mp, const int* flag, int* slens){
  int b = blockIdx.x*256 + threadIdx.x;
  if (b >= B_) return;
  int cnt = 0;
  if (*flag){
    const unsigned char* m = (const unsigned char*)mp;
    for (int s=0;s<S_;s++) cnt += (m[b*S_+s] != 0);
  } else {
    const int* m = (const int*)mp;
    for (int s=0;s<S_;s++) cnt += (m[b*S_+s] != 0);
  }
  slens[b] = cnt - 1;
}

// ---- convert W_ih to bf16; btot = b_ih + b_hh ----
__global__ void k_buildw(const float* wih, const float* bih, const float* bhh,
                         unsigned short* Wihbf, float* btot){
  int i = blockIdx.x*256 + threadIdx.x;
  if (i < G4*KX) Wihbf[i] = f2bf_(wih[i]);
  if (i < G4) btot[i] = bih[i] + bhh[i];
}

// ---- repack W_hh to per-(wave16,frag,lane) linear FP8 (e4m3 OCP) layout ----
// frag c = q*8+kt (q=gate, kt=k-tile). Ww8[((w*32+c)*64+lane)*8 + e] =
//   fp8(Whh[q*256 + w*16 + (lane&15)][kt*32 + (lane>>4)*8 + e]).  256 KB total.
__global__ void k_packw(const float* __restrict__ whh, unsigned char* __restrict__ Ww8){
  int idx = blockIdx.x*256 + threadIdx.x;   // 0..32767
  if (idx >= 32768) return;
  int lane = idx & 63, c = (idx>>6)&31, w = idx>>11;   // w 0..15
  int q = c>>3, kt = c&7, l16 = lane&15, quad = lane>>4;
  int row = q*256 + w*16 + l16;
  int col = kt*32 + quad*8;
  const float* s = whh + (size_t)row*256 + col;
  unsigned lo, hi;
  lo = __builtin_amdgcn_cvt_pk_fp8_f32(s[0], s[1], 0, 0);
  lo = __builtin_amdgcn_cvt_pk_fp8_f32(s[2], s[3], lo, 1);
  hi = __builtin_amdgcn_cvt_pk_fp8_f32(s[4], s[5], 0, 0);
  hi = __builtin_amdgcn_cvt_pk_fp8_f32(s[6], s[7], hi, 1);
  uint2 v; v.x = lo; v.y = hi;
  *(uint2*)(Ww8 + (size_t)idx*8) = v;
}

// ---- Gx = X @ W_ih^T + btot, bf16 MFMA; TIME-MAJOR output ----
__global__ __launch_bounds__(256) void k_gx(
    const int* __restrict__ loc, const int* __restrict__ usr,
    const int* __restrict__ wdy, const int* __restrict__ sm,
    const float* __restrict__ loct, const float* __restrict__ usert,
    const float* __restrict__ hourt, const float* __restrict__ wdt,
    const unsigned short* __restrict__ Wihbf, const float* __restrict__ btot,
    unsigned short* __restrict__ Gx){
  __shared__ unsigned short As[128][40];
  int tid = threadIdx.x;
  int n0 = blockIdx.x*128, m0 = blockIdx.y*128;
  int w = tid>>6, lane = tid&63;
  int quad = lane>>4, l16 = lane&15;
  int mw = (w>>1)*64, nw = (w&1)*64;
  f32x4 acc[4][4] = {};
  int r0 = tid>>2, seg = tid&3;
  for (int kt=0; kt<14; kt++){
    int k0 = kt*32;
    int kc = k0 + seg*8;
    #pragma unroll
    for (int rr=0; rr<2; rr++){
      int r = r0 + rr*64;
      int row = m0 + r;
      const float* src;
      if (kc < 256)      src = loct  + (size_t)loc[row]*256 + kc;
      else if (kc < 320) src = usert + (size_t)usr[row]*64 + (kc-256);
      else if (kc < 384) { int s = sm[row]; int hh = s/60; if (hh>24) hh=24; if (hh<0) hh=0;
                           src = hourt + (size_t)hh*64 + (kc-320); }
      else               src = wdt   + (size_t)wdy[row]*64 + (kc-384);
      float4 v0 = *(const float4*)(src);
      float4 v1 = *(const float4*)(src+4);
      short8 pk;
      pk[0]=f2bf_(v0.x); pk[1]=f2bf_(v0.y); pk[2]=f2bf_(v0.z); pk[3]=f2bf_(v0.w);
      pk[4]=f2bf_(v1.x); pk[5]=f2bf_(v1.y); pk[6]=f2bf_(v1.z); pk[7]=f2bf_(v1.w);
      *(short8*)&As[r][seg*8] = pk;
    }
    __syncthreads();
    short8 bfrag[4], afrag[4];
    #pragma unroll
    for (int nt=0; nt<4; nt++)
      bfrag[nt] = *(const short8*)(Wihbf + (size_t)(n0+nw+nt*16+l16)*KX + k0 + quad*8);
    #pragma unroll
    for (int mt=0; mt<4; mt++)
      afrag[mt] = *(const short8*)&As[mw+mt*16+l16][quad*8];
    #pragma unroll
    for (int mt=0; mt<4; mt++)
      #pragma unroll
      for (int nt=0; nt<4; nt++)
        acc[mt][nt] = __builtin_amdgcn_mfma_f32_16x16x32_bf16(afrag[mt], bfrag[nt], acc[mt][nt], 0, 0, 0);
    __syncthreads();
  }
  #pragma unroll
  for (int nt=0; nt<4; nt++){
    int col = n0 + nw + nt*16 + l16;
    float bv = btot[col];
    #pragma unroll
    for (int mt=0; mt<4; mt++){
      #pragma unroll
      for (int i=0; i<4; i++){
        int row = m0 + mw + mt*16 + quad*4 + i;   // row = b*S + t
        int bb = row >> 8, tt = row & 255;
        Gx[((size_t)tt*B_ + bb)*G4 + col] = f2bf_(acc[mt][nt][i] + bv);
      }
    }
  }
}

// ---- persistent LSTM, FP8, 16-wave blocks for 4 waves/SIMD TLP. ----
// 32 blocks x 1024 thr. Wave w owns d-slice [w*16,w*16+16), all 4 gates:
// 32 frags x 512B; c0..7 LDS-static (64KB block), c8..31 streamed to regs in
// three 8-frag single-use groups with TAIL-COUNTED vmcnt (G0@8, G1@10, G2@2 —
// counts ops issued AFTER the group: robust to ctx stores). Gx[t+1] prefetch
// (2 gld_lds/wave) stays IN FLIGHT across both barriers — no vmcnt(0) in loop.
// LDS = 4K h + 2x32K gx + 64K weights = 135168B (proven). Raw s_barrier only.
__global__ __launch_bounds__(1024, 4) void k_lstm(
    const unsigned short* __restrict__ Gx,      // [S][B][1024] time-major bf16
    const unsigned char* __restrict__ Ww8,      // repacked fp8 weights
    float* __restrict__ ctx, const int* __restrict__ slens){
  __shared__ unsigned char h_s[16*256];         // 4 KB fp8 h, XOR-swizzled 8B chunks
  __shared__ unsigned short gx_s[2][16*1024];   // 64 KB bf16, double-buffered
  __shared__ unsigned char whhs[16*4096];       // 64 KB static: frags c0..7 per wave
  int tid = threadIdx.x;
  int w = tid >> 6, lane = tid & 63;
  int quad = lane >> 4, l16 = lane & 15;
  int b0 = blockIdx.x * 16;
  int dw = w * 16;

  for (int i = tid; i < 16*256; i += 1024) h_s[i] = 0;

  // static fill: frags c0..7 (gate i, kt0..7) = 4 KB/wave, 4 calls
  #pragma unroll
  for (int j=0;j<4;j++)
    gld_lds16_(Ww8 + (size_t)w*16384 + j*1024 + lane*16, &whhs[w*4096 + j*1024]);

  float cst[4] = {0.f,0.f,0.f,0.f};
  int slq[4];
  #pragma unroll
  for (int i=0;i<4;i++) slq[i] = slens[b0 + quad*4 + i];

  // stage gx for t=0 into buf0 (left outstanding across the barrier)
  {
    const unsigned short* src = Gx + (size_t)b0*G4 + w*1024 + lane*8;
    #pragma unroll
    for (int j=0;j<2;j++) gld_lds16_(src + j*512, &gx_s[0][w*1024 + j*512]);
  }
  asm volatile("s_waitcnt vmcnt(2) lgkmcnt(0)" ::: "memory");  // whhs done; gx0 in flight
  __builtin_amdgcn_sched_barrier(0);
  __builtin_amdgcn_s_barrier();

  for (int t=0; t<S_; t++){
    int cur = t & 1;
    // laundered uniform base (SGPR-legal); offsets applied after
    unsigned long long pb = (unsigned long long)Ww8;
    asm volatile("" : "+s"(pb));
    const unsigned char* sb = (const unsigned char*)pb + (size_t)w*16384 + lane*8;

    long long G0[8], G1[8], G2[8];
    #pragma unroll
    for (int j=0;j<8;j++) G0[j] = *(const long long*)(sb + (size_t)(8+j)*512);
    #pragma unroll
    for (int j=0;j<8;j++) G1[j] = *(const long long*)(sb + (size_t)(16+j)*512);
    __builtin_amdgcn_sched_barrier(0);

    // a-frags + static MFMAs (gate i) — covers G0/G1 issue latency
    long long af[8];
    #pragma unroll
    for (int kt=0;kt<8;kt++)
      af[kt] = *(const long long*)&h_s[l16*256 + ((((kt<<2)|quad) ^ (l16&7))<<3)];
    f32x4 acc[4] = {};
    #pragma unroll
    for (int c=0;c<8;c++){
      long long bfr = *(const long long*)&whhs[w*4096 + c*512 + lane*8];
      acc[0] = __builtin_amdgcn_mfma_f32_16x16x32_fp8_fp8(af[c], bfr, acc[0], 0, 0, 0);
    }
    __builtin_amdgcn_sched_barrier(0);

    // G0 done <=> remaining <= |after G0| = G1(8)
    asm volatile("s_waitcnt vmcnt(8)" ::: "memory");
    __builtin_amdgcn_sched_barrier(0);
    #pragma unroll
    for (int j=0;j<8;j++)
      acc[1] = __builtin_amdgcn_mfma_f32_16x16x32_fp8_fp8(af[j], G0[j], acc[1], 0, 0, 0);
    __builtin_amdgcn_sched_barrier(0);

    // issue G2 + next-step gx prefetch (always issued: uniform vmcnt tails)
    #pragma unroll
    for (int j=0;j<8;j++) G2[j] = *(const long long*)(sb + (size_t)(24+j)*512);
    {
      int tn = (t < S_-1) ? t+1 : t;
      const unsigned short* src = Gx + ((size_t)tn*B_ + b0)*G4 + w*1024 + lane*8;
      #pragma unroll
      for (int j=0;j<2;j++) gld_lds16_(src + j*512, &gx_s[cur^1][w*1024 + j*512]);
    }
    __builtin_amdgcn_sched_barrier(0);

    // G1 done <=> remaining <= G2(8)+gx(2) = 10
    asm volatile("s_waitcnt vmcnt(10)" ::: "memory");
    __builtin_amdgcn_sched_barrier(0);
    #pragma unroll
    for (int j=0;j<8;j++)
      acc[2] = __builtin_amdgcn_mfma_f32_16x16x32_fp8_fp8(af[j], G1[j], acc[2], 0, 0, 0);
    __builtin_amdgcn_sched_barrier(0);

    // G2 done <=> remaining <= gx(2); gx[cur] (head of queue) long done
    asm volatile("s_waitcnt vmcnt(2)" ::: "memory");
    __builtin_amdgcn_sched_barrier(0);
    #pragma unroll
    for (int j=0;j<8;j++)
      acc[3] = __builtin_amdgcn_mfma_f32_16x16x32_fp8_fp8(af[j], G2[j], acc[3], 0, 0, 0);

    // pre-epilogue: LDS reads retired; gx[cur^1] prefetch stays in flight
    asm volatile("s_waitcnt lgkmcnt(0)" ::: "memory");
    __builtin_amdgcn_sched_barrier(0);
    __builtin_amdgcn_s_barrier();

    // epilogue: 4 cell updates/thread (rows quad*4+i, dim d)
    const unsigned int* gxw = (const unsigned int*)&gx_s[cur][0];
    int half = l16 & 1;
    int d = dw + l16;
    int du = w*8 + (l16>>1);
    int chunk = d >> 3;
    #pragma unroll
    for (int i=0;i<4;i++){
      int r = quad*4 + i;
      int base = r*512 + du;
      unsigned int u0 = gxw[base];
      unsigned int u1 = gxw[base + 128];
      unsigned int u2 = gxw[base + 256];
      unsigned int u3 = gxw[base + 384];
      unsigned short s0 = half ? (unsigned short)(u0>>16) : (unsigned short)(u0&0xffff);
      unsigned short s1 = half ? (unsigned short)(u1>>16) : (unsigned short)(u1&0xffff);
      unsigned short s2 = half ? (unsigned short)(u2>>16) : (unsigned short)(u2&0xffff);
      unsigned short s3 = half ? (unsigned short)(u3>>16) : (unsigned short)(u3&0xffff);
      float gi = acc[0][i] + bf2f_(s0);
      float gf = acc[1][i] + bf2f_(s1);
      float gg = acc[2][i] + bf2f_(s2);
      float go = acc[3][i] + bf2f_(s3);
      float cn = fsig_(gf)*cst[i] + fsig_(gi)*ftanh2_(gg);
      float hn = fsig_(go)*ftanh2_(cn);
      cst[i] = cn;
      int p8 = __builtin_amdgcn_cvt_pk_fp8_f32(hn, hn, 0, 0);
      h_s[r*256 + ((chunk ^ (r&7))<<3) + (d&7)] = (unsigned char)(p8 & 0xff);
      if (t == slq[i]) ctx[(size_t)(b0 + r)*D_ + d] = hn;
    }

    // end barrier: h_s writes visible before next step's af reads
    asm volatile("s_waitcnt lgkmcnt(0)" ::: "memory");
    __builtin_amdgcn_sched_barrier(0);
    __builtin_amdgcn_s_barrier();
  }
}

// ---- newhid = gelu(ctx @ np_W1^T + np_b1); mix ----
__global__ void k_post1(const float* __restrict__ ctx, const float* __restrict__ W1,
                        const float* __restrict__ b1, const float* __restrict__ mxW,
                        const float* __restrict__ mxb, float* newhid, float* mixv){
  __shared__ float cs[256];
  __shared__ float red[256];
  int b = blockIdx.x, tid = threadIdx.x;
  cs[tid] = ctx[(size_t)b*D_ + tid];
  __syncthreads();
  float a = b1[tid];
  const float* wr = W1 + (size_t)tid*D_;
  for (int k=0; k<D_; k++) a += cs[k]*wr[k];
  newhid[(size_t)b*D_ + tid] = geluf_(a);
  red[tid] = cs[tid]*mxW[tid];
  __syncthreads();
  for (int s=128; s>0; s>>=1){ if (tid<s) red[tid]+=red[tid+s]; __syncthreads(); }
  if (tid==0) mixv[b] = sigmoidf_(red[0]+mxb[0])*0.9f + 0.05f;
}

// ---- recent-location scores + dedup/keep ----
__global__ void k_recent(const int* __restrict__ loc, const int* __restrict__ sm,
                         const int* __restrict__ slens, const float* __restrict__ loct,
                         const float* __restrict__ W1, const float* __restrict__ b1,
                         const float* __restrict__ W2, const float* __restrict__ b2,
                         float* scores, int* rlocs, int* keep){
  __shared__ int rl[5], vs[5];
  __shared__ float td[5];
  __shared__ float red[128];
  int b = blockIdx.x, tid = threadIdx.x;
  int sl = slens[b];
  if (tid < 5){
    int idx = sl - tid;
    int v = idx >= 0;
    int ic = v ? idx : 0;
    rl[tid] = loc[b*S_ + ic];
    vs[tid] = v;
    int cur = sm[b*S_ + sl];
    td[tid] = (float)(cur - sm[b*S_ + ic]) * (1.0f/1440.0f);
  }
  __syncthreads();
  for (int j=0; j<5; j++){
    const float* lrow = loct + (size_t)rl[j]*D_;
    const float* wr = W1 + (size_t)tid*258;
    float a = b1[tid];
    for (int k=0; k<D_; k++) a += lrow[k]*wr[k];
    a += td[j]*wr[256] + (float)j*wr[257];
    red[tid] = geluf_(a)*W2[tid];
    __syncthreads();
    for (int s=64; s>0; s>>=1){ if (tid<s) red[tid]+=red[tid+s]; __syncthreads(); }
    if (tid==0) scores[b*5+j] = red[0] + b2[0];
    __syncthreads();
  }
  if (tid==0){
    for (int j=0; j<5; j++){
      int dup = 0;
      for (int k=0; k<j; k++) dup |= (rl[j]==rl[k]) && vs[k];
      keep[b*5+j] = vs[j] && !dup;
      rlocs[b*5+j] = rl[j];
    }
  }
}

// ---- big fused head ----
__global__ __launch_bounds__(256) void k_final(const float* __restrict__ newhid,
    const float* __restrict__ W2, const float* __restrict__ b2,
    const float* __restrict__ mixv, float* __restrict__ out){
  __shared__ float Hs[16][260];
  __shared__ float Wl[64][65];
  int tid = threadIdx.x;
  int l0 = blockIdx.x*64, b0 = blockIdx.y*16;
  int ll = tid & 63, bq = tid >> 6;
  #pragma unroll
  for (int r=0; r<16; r++) Hs[r][tid] = newhid[(size_t)(b0+r)*D_ + tid];
  float acc[4] = {0.f,0.f,0.f,0.f};
  for (int kt=0; kt<4; kt++){
    int k0 = kt*64;
    __syncthreads();
    #pragma unroll
    for (int r=0; r<4; r++){
      int row = 4*r + bq;
      int l = l0 + row;
      Wl[row][ll] = (l < NLOC) ? W2[(size_t)l*D_ + k0 + ll] : 0.f;
    }
    __syncthreads();
    #pragma unroll
    for (int kk=0; kk<64; kk++){
      float wv = Wl[ll][kk];
      #pragma unroll
      for (int bi=0; bi<4; bi++) acc[bi] += wv * Hs[bq*4+bi][k0+kk];
    }
  }
  int l = l0 + ll;
  if (l < NLOC){
    float bias = b2[l];
    #pragma unroll
    for (int bi=0; bi<4; bi++){
      int b = b0 + bq*4 + bi;
      float mx = mixv[b];
      out[(size_t)b*NLOC + l] = mx*NEGV + (1.0f-mx)*(acc[bi] + bias);
    }
  }
}

// ---- overwrite kept recent locations ----
__global__ void k_scatter(const float* __restrict__ newhid, const float* __restrict__ W2,
                          const float* __restrict__ b2, const float* __restrict__ mixv,
                          const float* __restrict__ scores, const int* __restrict__ rlocs,
                          const int* __restrict__ keep, float* out){
  int b = blockIdx.x, lane = threadIdx.x;
  float mx = mixv[b];
  for (int j=0; j<5; j++){
    if (!keep[b*5+j]) continue;
    int rl = rlocs[b*5+j];
    const float* wr = W2 + (size_t)rl*D_;
    const float* hr = newhid + (size_t)b*D_;
    float a = 0.f;
    #pragma unroll
    for (int q=0; q<4; q++){ int k = lane + 64*q; a += hr[k]*wr[k]; }
    #pragma unroll
    for (int off=32; off>0; off>>=1) a += __shfl_xor(a, off, 64);
    if (lane==0)
      out[(size_t)b*NLOC + rl] = mx*scores[b*5+j] + (1.0f-mx)*(a + b2[rl]);
  }
}

extern "C" void kernel_launch(void* const* d_in, const int* in_sizes, int n_in,
                              void* d_out, int out_size, void* d_ws, size_t ws_size,
                              hipStream_t stream){
  const int* locations   = (const int*)d_in[0];
  const int* users       = (const int*)d_in[1];
  const int* weekdays    = (const int*)d_in[2];
  const int* start_mins  = (const int*)d_in[3];
  const void* mask       = d_in[4];
  const float* loc_table = (const float*)d_in[5];
  const float* user_table= (const float*)d_in[6];
  const float* hour_table= (const float*)d_in[7];
  const float* wd_table  = (const float*)d_in[8];
  const float* W_ih      = (const float*)d_in[9];
  const float* W_hh      = (const float*)d_in[10];
  const float* b_ih      = (const float*)d_in[11];
  const float* b_hh      = (const float*)d_in[12];
  const float* sc_W1     = (const float*)d_in[13];
  const float* sc_b1     = (const float*)d_in[14];
  const float* sc_W2     = (const float*)d_in[15];
  const float* sc_b2     = (const float*)d_in[16];
  const float* np_W1     = (const float*)d_in[17];
  const float* np_b1     = (const float*)d_in[18];
  const float* np_W2     = (const float*)d_in[19];
  const float* np_b2     = (const float*)d_in[20];
  const float* mx_W      = (const float*)d_in[21];
  const float* mx_b      = (const float*)d_in[22];
  float* out = (float*)d_out;

  char* w = (char*)d_ws;
  size_t o = 0;
  auto alloc = [&](size_t bytes)->void*{ void* p = w + o; o += (bytes + 255) & ~(size_t)255; return p; };
  unsigned short* Gx    = (unsigned short*)alloc((size_t)B_*S_*G4*sizeof(short)); // 268 MB bf16, time-major
  unsigned short* Wihbf = (unsigned short*)alloc((size_t)G4*KX*sizeof(short));
  unsigned char*  Ww8   = (unsigned char*)alloc((size_t)G4*D_);                   // fp8 repacked Whh (256 KB)
  float* btot   = (float*)alloc((size_t)G4*sizeof(float));
  float* ctx    = (float*)alloc((size_t)B_*D_*sizeof(float));
  float* newhid = (float*)alloc((size_t)B_*D_*sizeof(float));
  float* mixv   = (float*)alloc((size_t)B_*sizeof(float));
  float* scores = (float*)alloc((size_t)B_*5*sizeof(float));
  int*   slens  = (int*)alloc((size_t)B_*sizeof(int));
  int*   rlocs  = (int*)alloc((size_t)B_*5*sizeof(int));
  int*   keep   = (int*)alloc((size_t)B_*5*sizeof(int));
  int*   flag   = (int*)alloc(sizeof(int));

  k_init<<<1, 64, 0, stream>>>(flag);
  k_detect<<<512, 256, 0, stream>>>((const unsigned char*)mask, flag);
  k_seqlen<<<2, 256, 0, stream>>>(mask, flag, slens);
  k_buildw<<<1792, 256, 0, stream>>>(W_ih, b_ih, b_hh, Wihbf, btot);
  k_packw<<<128, 256, 0, stream>>>(W_hh, Ww8);
  k_gx<<<dim3(8,1024), 256, 0, stream>>>(locations, users, weekdays, start_mins,
                                         loc_table, user_table, hour_table, wd_table,
                                         Wihbf, btot, Gx);
  k_lstm<<<32, 1024, 0, stream>>>(Gx, Ww8, ctx, slens);
  k_post1<<<512, 256, 0, stream>>>(ctx, np_W1, np_b1, mx_W, mx_b, newhid, mixv);
  k_recent<<<512, 128, 0, stream>>>(locations, start_mins, slens, loc_table,
                                    sc_W1, sc_b1, sc_W2, sc_b2, scores, rlocs, keep);
  k_final<<<dim3(782,32), 256, 0, stream>>>(newhid, np_W2, np_b2, mixv, out);
  k_scatter<<<512, 64, 0, stream>>>(newhid, np_W2, np_b2, mixv, scores, rlocs, keep, out);
}